// Round 1
// baseline (11422.645 us; speedup 1.0000x reference)
//
#include <hip/hip_runtime.h>
#include <math.h>

#define kN 30000
#define kE 240000
#define kD 64
#define kG 64
#define kHSZ (1 << 19)
#define kNW 938  // ceil(30000/32)

// ---------------- embed: z = x @ W_embed ----------------
__global__ __launch_bounds__(256) void k_embed(const float* __restrict__ x,
                                               const float* __restrict__ W,
                                               float* __restrict__ z) {
  __shared__ float sW[128 * 64];  // 32 KB
  int tid = threadIdx.x;
  for (int i = tid; i < 128 * 64; i += 256) sW[i] = W[i];
  __syncthreads();
  int lane = tid & 63, sub = tid >> 6;
  int row0 = blockIdx.x * 16;
  for (int r = sub; r < 16; r += 4) {
    int n = row0 + r;
    if (n >= kN) continue;
    const float* xr = x + (size_t)n * 128;
    float acc = 0.f;
#pragma unroll
    for (int k = 0; k < 128; ++k) acc = fmaf(xr[k], sW[k * 64 + lane], acc);
    z[(size_t)n * 64 + lane] = acc;
  }
}

// ---------------- graph pooling: embs[g][d] += z[n][d] ----------------
__global__ void k_pool(const float* __restrict__ z, const int* __restrict__ batch,
                       float* __restrict__ embs_out) {
  int idx = blockIdx.x * 256 + threadIdx.x;
  if (idx >= kN * 64) return;
  int n = idx >> 6, d = idx & 63;
  float v = z[idx];
  if (v != 0.f) atomicAdd(&embs_out[batch[n] * 64 + d], v);
}

// ---------------- per-layer state init ----------------
__global__ void k_init_layer(int* __restrict__ cluster, int* __restrict__ partner,
                             float* __restrict__ mult, int* __restrict__ nmask,
                             int set_ones) {
  int n = blockIdx.x * 256 + threadIdx.x;
  if (n >= kN) return;
  cluster[n] = n;
  partner[n] = -1;
  mult[n] = 1.0f;
  if (set_ones) nmask[n] = 1;
}

// ---------------- raw edge score + segment max (wave per edge) ----------------
__global__ __launch_bounds__(256) void k_raw(const float* __restrict__ z,
                                             const int* __restrict__ esrc,
                                             const int* __restrict__ edst,
                                             const float* __restrict__ We,
                                             const float* __restrict__ be, int layer,
                                             const int* __restrict__ emask,
                                             float* __restrict__ raws,
                                             unsigned int* __restrict__ m_enc) {
  int wv = threadIdx.x >> 6, lane = threadIdx.x & 63;
  int e = blockIdx.x * 4 + wv;
  if (e >= kE) return;
  if (emask && !emask[e]) return;
  int s = esrc[e], t = edst[e];
  float f = z[(size_t)s * 64 + lane] * We[layer * 128 + lane] +
            z[(size_t)t * 64 + lane] * We[layer * 128 + 64 + lane];
#pragma unroll
  for (int m = 32; m > 0; m >>= 1) f += __shfl_xor(f, m, 64);
  if (lane == 0) {
    float raw = f + be[layer];
    raws[e] = raw;
    unsigned int u = __float_as_uint(raw);
    u = (u & 0x80000000u) ? ~u : (u | 0x80000000u);  // order-preserving encode
    atomicMax(&m_enc[t], u);
  }
}

// ---------------- exp + denominator ----------------
__global__ void k_exp(const float* __restrict__ raws, const unsigned int* __restrict__ m_enc,
                      const int* __restrict__ edst, const int* __restrict__ emask,
                      float* __restrict__ exs, double* __restrict__ den) {
  int e = blockIdx.x * 256 + threadIdx.x;
  if (e >= kE) return;
  if (emask && !emask[e]) {
    exs[e] = 0.f;
    return;
  }
  int t = edst[e];
  unsigned int u = m_enc[t];
  u = (u & 0x80000000u) ? (u ^ 0x80000000u) : ~u;  // decode
  float m = __uint_as_float(u);
  float ex = expf(raws[e] - m);
  exs[e] = ex;
  atomicAdd(&den[t], (double)ex);
}

// ---------------- score = ex/den + 0.5, build worklist ----------------
__global__ void k_scoref(const float* __restrict__ exs, const double* __restrict__ den,
                         const int* __restrict__ esrc, const int* __restrict__ edst,
                         const int* __restrict__ emask, const int* __restrict__ nmask,
                         float* __restrict__ eplus, int* __restrict__ wl,
                         int* __restrict__ cnt) {
  int e = blockIdx.x * 256 + threadIdx.x;
  if (e >= kE) return;
  if (emask && !emask[e]) {
    eplus[e] = 0.f;
    return;
  }
  int t = edst[e];
  float dn = (float)den[t];
  float ep = exs[e] / fmaxf(dn, 1e-16f) + 0.5f;
  eplus[e] = ep;
  int s = esrc[e];
  if (nmask[s] && nmask[t]) {
    int p = atomicAdd(cnt, 1);
    wl[p] = e;
  }
}

// ---------------- greedy contraction == iterated locally-dominant matching ----
__global__ __launch_bounds__(1024) void k_match(
    const int* __restrict__ esrc, const int* __restrict__ edst,
    const float* __restrict__ eplus, unsigned long long* __restrict__ best,
    int* __restrict__ wlA, int* __restrict__ wlB, int* __restrict__ cluster,
    int* __restrict__ partner, float* __restrict__ mult, int* __restrict__ nmask,
    const int* __restrict__ cnt) {
  __shared__ unsigned int avail[kNW];
  __shared__ int sh_n, sh_out;
  int tid = threadIdx.x;
  // init avail bitmask from node mask
  for (int w = tid; w < kNW; w += 1024) {
    unsigned int bits = 0u;
    int base = w << 5;
    for (int j = 0; j < 32; ++j) {
      int n = base + j;
      if (n < kN && nmask[n]) bits |= (1u << j);
    }
    avail[w] = bits;
  }
  if (tid == 0) sh_n = cnt[0];
  __syncthreads();
  int n = sh_n;
  int* cur = wlA;
  int* nxt = wlB;
  for (int round = 0; round < 100000 && n > 0; ++round) {
    // phase 1: reset best for endpoints of live edges
    for (int i = tid; i < n; i += 1024) {
      int e = cur[i];
      int s = esrc[e], t = edst[e];
      if (((avail[s >> 5] >> (s & 31)) & 1u) && ((avail[t >> 5] >> (t & 31)) & 1u)) {
        __hip_atomic_store(&best[s], ~0ULL, __ATOMIC_RELAXED, __HIP_MEMORY_SCOPE_AGENT);
        __hip_atomic_store(&best[t], ~0ULL, __ATOMIC_RELAXED, __HIP_MEMORY_SCOPE_AGENT);
      }
    }
    __syncthreads();
    // phase 2: atomicMin of 64-bit key (score desc, edge id asc)
    for (int i = tid; i < n; i += 1024) {
      int e = cur[i];
      int s = esrc[e], t = edst[e];
      if (((avail[s >> 5] >> (s & 31)) & 1u) && ((avail[t >> 5] >> (t & 31)) & 1u)) {
        unsigned long long key =
            ((unsigned long long)(~__float_as_uint(eplus[e])) << 32) | (unsigned int)e;
        __hip_atomic_fetch_min(&best[s], key, __ATOMIC_RELAXED, __HIP_MEMORY_SCOPE_AGENT);
        if (t != s)
          __hip_atomic_fetch_min(&best[t], key, __ATOMIC_RELAXED, __HIP_MEMORY_SCOPE_AGENT);
      }
    }
    if (tid == 0) sh_out = 0;
    __syncthreads();
    // phase 3: dominant edges match; survivors compact into nxt
    for (int i = tid; i < n; i += 1024) {
      int e = cur[i];
      int s = esrc[e], t = edst[e];
      if (!((avail[s >> 5] >> (s & 31)) & 1u) || !((avail[t >> 5] >> (t & 31)) & 1u))
        continue;  // dead, drop
      unsigned long long key =
          ((unsigned long long)(~__float_as_uint(eplus[e])) << 32) | (unsigned int)e;
      bool ok = (__hip_atomic_load(&best[s], __ATOMIC_RELAXED, __HIP_MEMORY_SCOPE_AGENT) == key);
      if (ok && t != s)
        ok = (__hip_atomic_load(&best[t], __ATOMIC_RELAXED, __HIP_MEMORY_SCOPE_AGENT) == key);
      if (ok) {
        atomicAnd(&avail[s >> 5], ~(1u << (s & 31)));
        atomicAnd(&avail[t >> 5], ~(1u << (t & 31)));
        cluster[t] = s;
        partner[s] = t;
        mult[s] = eplus[e];
        if (t != s) nmask[t] = 0;
      } else {
        int p = atomicAdd(&sh_out, 1);
        nxt[p] = e;
      }
    }
    __syncthreads();
    n = sh_out;
    int* tmp = cur;
    cur = nxt;
    nxt = tmp;
  }
}

// ---------------- merged features: <=2 members per cluster, no atomics -------
__global__ void k_newx(const float* __restrict__ z, const int* __restrict__ cluster,
                       const int* __restrict__ partner, const float* __restrict__ mult,
                       float* __restrict__ zo) {
  int idx = blockIdx.x * 256 + threadIdx.x;
  if (idx >= kN * 64) return;
  int n = idx >> 6, d = idx & 63;
  float v = 0.f;
  if (cluster[n] == n) {
    v = z[idx];
    int p = partner[n];
    if (p >= 0 && p != n) v += z[(size_t)p * 64 + d];
    v *= mult[n];
  }
  zo[idx] = v;
}

// ---------------- edge remap + hash-dedup (keep min edge id per key) ---------
__global__ void k_remap(const int* __restrict__ esrc, const int* __restrict__ edst,
                        const int* __restrict__ cluster, const int* __restrict__ emask,
                        int* __restrict__ esrcn, int* __restrict__ edstn,
                        int* __restrict__ hkey, int* __restrict__ hmin,
                        int* __restrict__ hslot) {
  int e = blockIdx.x * 256 + threadIdx.x;
  if (e >= kE) return;
  int ns = cluster[esrc[e]];
  int nt = cluster[edst[e]];
  esrcn[e] = ns;
  edstn[e] = nt;
  if (emask && !emask[e]) return;
  int key = ns * kN + nt;  // < 9e8, fits int32
  unsigned int h = (((unsigned int)key * 2654435761u) >> 13) & (kHSZ - 1);
  while (true) {
    int old = atomicCAS(&hkey[h], -1, key);
    if (old == -1 || old == key) break;
    h = (h + 1) & (kHSZ - 1);
  }
  atomicMin(&hmin[h], e);
  hslot[e] = (int)h;
}

__global__ void k_dedup(const int* __restrict__ emask, const int* __restrict__ hmin,
                        const int* __restrict__ hslot, int* __restrict__ emaskn) {
  int e = blockIdx.x * 256 + threadIdx.x;
  if (e >= kE) return;
  int keep = 0;
  if (!emask || emask[e]) keep = (hmin[hslot[e]] == e) ? 1 : 0;
  emaskn[e] = keep;
}

// ---------------- final FC: out = concat(embs) @ W_fc + b_fc ----------------
__global__ void k_final(const float* __restrict__ embs, const float* __restrict__ Wfc,
                        const float* __restrict__ bfc, float* __restrict__ out) {
  int tid = threadIdx.x;
  if (tid >= kG * 10) return;
  int g = tid / 10, c = tid % 10;
  float acc = bfc[c];
  for (int l = 0; l < 3; ++l)
    for (int d = 0; d < 64; ++d)
      acc += embs[l * (kG * 64) + g * 64 + d] * Wfc[(l * 64 + d) * 10 + c];
  out[g * 10 + c] = acc;
}

extern "C" void kernel_launch(void* const* d_in, const int* in_sizes, int n_in,
                              void* d_out, int out_size, void* d_ws, size_t ws_size,
                              hipStream_t stream) {
  (void)in_sizes; (void)n_in; (void)out_size; (void)ws_size;
  const float* x = (const float*)d_in[0];
  const int* ei = (const int*)d_in[1];  // [2,E]: src = ei, dst = ei + kE
  const int* batch = (const int*)d_in[2];
  const float* Wemb = (const float*)d_in[3];
  const float* We = (const float*)d_in[4];
  const float* be = (const float*)d_in[5];
  const float* Wfc = (const float*)d_in[6];
  const float* bfc = (const float*)d_in[7];
  float* out = (float*)d_out;

  char* ws = (char*)d_ws;
  size_t off = 0;
  auto alloc = [&](size_t bytes) -> void* {
    void* p = ws + off;
    off = (off + bytes + 255) & ~(size_t)255;
    return p;
  };
  float* z0 = (float*)alloc((size_t)kN * 64 * 4);
  float* z1 = (float*)alloc((size_t)kN * 64 * 4);
  float* raws = (float*)alloc((size_t)kE * 4);
  float* exs = (float*)alloc((size_t)kE * 4);
  float* eplus = (float*)alloc((size_t)kE * 4);
  unsigned int* m_enc = (unsigned int*)alloc((size_t)kN * 4);
  double* den = (double*)alloc((size_t)kN * 8);
  unsigned long long* best = (unsigned long long*)alloc((size_t)kN * 8);
  int* cluster = (int*)alloc((size_t)kN * 4);
  int* partner = (int*)alloc((size_t)kN * 4);
  float* mult = (float*)alloc((size_t)kN * 4);
  int* nmask = (int*)alloc((size_t)kN * 4);
  int* esrc1 = (int*)alloc((size_t)kE * 4);
  int* edst1 = (int*)alloc((size_t)kE * 4);
  int* emask1 = (int*)alloc((size_t)kE * 4);
  int* wlA = (int*)alloc((size_t)kE * 4);
  int* wlB = (int*)alloc((size_t)kE * 4);
  int* hkey = (int*)alloc((size_t)kHSZ * 4);
  int* hmin = (int*)alloc((size_t)kHSZ * 4);
  float* embs = (float*)alloc((size_t)3 * kG * 64 * 4);
  int* cnt = (int*)alloc(256);

  const int gN = (kN + 255) / 256;          // 118
  const int gND = (kN * 64) / 256;          // 7500
  const int gE = (kE + 255) / 256;          // 938
  const int gEW = kE / 4;                   // 60000 (wave per edge)

  hipMemsetAsync(embs, 0, (size_t)3 * kG * 64 * 4, stream);

  k_embed<<<kN / 16, 256, 0, stream>>>(x, Wemb, z0);
  k_pool<<<gND, 256, 0, stream>>>(z0, batch, embs);  // embs[0]

  // ---------------- layer 1 ----------------
  k_init_layer<<<gN, 256, 0, stream>>>(cluster, partner, mult, nmask, 1);
  hipMemsetAsync(m_enc, 0, (size_t)kN * 4, stream);
  hipMemsetAsync(den, 0, (size_t)kN * 8, stream);
  hipMemsetAsync(cnt, 0, 4, stream);
  hipMemsetAsync(hkey, 0xFF, (size_t)kHSZ * 4, stream);
  hipMemsetAsync(hmin, 0x7F, (size_t)kHSZ * 4, stream);
  k_raw<<<gEW, 256, 0, stream>>>(z0, ei, ei + kE, We, be, 0, nullptr, raws, m_enc);
  k_exp<<<gE, 256, 0, stream>>>(raws, m_enc, ei + kE, nullptr, exs, den);
  k_scoref<<<gE, 256, 0, stream>>>(exs, den, ei, ei + kE, nullptr, nmask, eplus, wlA, cnt);
  k_match<<<1, 1024, 0, stream>>>(ei, ei + kE, eplus, best, wlA, wlB, cluster, partner,
                                  mult, nmask, cnt);
  k_newx<<<gND, 256, 0, stream>>>(z0, cluster, partner, mult, z1);
  k_pool<<<gND, 256, 0, stream>>>(z1, batch, embs + kG * 64);  // embs[1]
  k_remap<<<gE, 256, 0, stream>>>(ei, ei + kE, cluster, nullptr, esrc1, edst1, hkey,
                                  hmin, wlA);
  k_dedup<<<gE, 256, 0, stream>>>(nullptr, hmin, wlA, emask1);

  // ---------------- layer 2 ----------------
  k_init_layer<<<gN, 256, 0, stream>>>(cluster, partner, mult, nmask, 0);
  hipMemsetAsync(m_enc, 0, (size_t)kN * 4, stream);
  hipMemsetAsync(den, 0, (size_t)kN * 8, stream);
  hipMemsetAsync(cnt, 0, 4, stream);
  k_raw<<<gEW, 256, 0, stream>>>(z1, esrc1, edst1, We, be, 1, emask1, raws, m_enc);
  k_exp<<<gE, 256, 0, stream>>>(raws, m_enc, edst1, emask1, exs, den);
  k_scoref<<<gE, 256, 0, stream>>>(exs, den, esrc1, edst1, emask1, nmask, eplus, wlA, cnt);
  k_match<<<1, 1024, 0, stream>>>(esrc1, edst1, eplus, best, wlA, wlB, cluster, partner,
                                  mult, nmask, cnt);
  k_newx<<<gND, 256, 0, stream>>>(z1, cluster, partner, mult, z0);
  k_pool<<<gND, 256, 0, stream>>>(z0, batch, embs + 2 * kG * 64);  // embs[2]

  k_final<<<1, 640, 0, stream>>>(embs, Wfc, bfc, out);
}

// Round 2
// 1354.644 us; speedup vs baseline: 8.4322x; 8.4322x over previous
//
#include <hip/hip_runtime.h>
#include <math.h>

#define kN 30000
#define kE 240000
#define kG 64
#define kHSZ (1 << 19)
#define kNW 938  // ceil(30000/32)
#define kMB 64
#define kMT 1024
#define kGSZ (kMB * kMT)
#define kSMALL 3072

// ---------------- atomic helpers (AGENT scope, bypass stale L1/L2) ----------
__device__ __forceinline__ int ald(const int* p) {
  return __hip_atomic_load(p, __ATOMIC_RELAXED, __HIP_MEMORY_SCOPE_AGENT);
}
__device__ __forceinline__ unsigned int aldu(const unsigned int* p) {
  return __hip_atomic_load(p, __ATOMIC_RELAXED, __HIP_MEMORY_SCOPE_AGENT);
}
__device__ __forceinline__ unsigned long long aldull(const unsigned long long* p) {
  return __hip_atomic_load(p, __ATOMIC_RELAXED, __HIP_MEMORY_SCOPE_AGENT);
}
__device__ __forceinline__ void ast(int* p, int v) {
  __hip_atomic_store(p, v, __ATOMIC_RELAXED, __HIP_MEMORY_SCOPE_AGENT);
}

// key: (round << 50) | order-preserving(score) << 18 | (262143 - e)
// atomicMax semantics = (newest round, highest score, lowest edge id) wins.
__device__ __forceinline__ unsigned long long mk_key(int r, float ep, int e) {
  unsigned int u = __float_as_uint(ep);
  u = (u & 0x80000000u) ? ~u : (u | 0x80000000u);
  return ((unsigned long long)r << 50) | ((unsigned long long)u << 18) |
         (unsigned long long)(262143 - e);
}

// centralized grid barrier: 64 co-resident WGs (16 VGPR / 4KB LDS => safe)
__device__ __forceinline__ void grid_bar(int* bar, int* gen) {
  __syncthreads();
  if (threadIdx.x == 0) {
    int g = ++(*gen);
    __hip_atomic_fetch_add(bar, 1, __ATOMIC_ACQ_REL, __HIP_MEMORY_SCOPE_AGENT);
    while (__hip_atomic_load(bar, __ATOMIC_ACQUIRE, __HIP_MEMORY_SCOPE_AGENT) < kMB * g)
      __builtin_amdgcn_s_sleep(2);
  }
  __syncthreads();
}

// ---------------- embed: z = x @ W_embed ----------------
__global__ __launch_bounds__(256) void k_embed(const float* __restrict__ x,
                                               const float* __restrict__ W,
                                               float* __restrict__ z) {
  __shared__ float sW[128 * 64];  // 32 KB
  int tid = threadIdx.x;
  for (int i = tid; i < 128 * 64; i += 256) sW[i] = W[i];
  __syncthreads();
  int lane = tid & 63, sub = tid >> 6;
  int row0 = blockIdx.x * 16;
  for (int r = sub; r < 16; r += 4) {
    int n = row0 + r;
    if (n >= kN) continue;
    const float* xr = x + (size_t)n * 128;
    float acc = 0.f;
#pragma unroll
    for (int k = 0; k < 128; ++k) acc = fmaf(xr[k], sW[k * 64 + lane], acc);
    z[(size_t)n * 64 + lane] = acc;
  }
}

// ---------------- graph pooling: embs[g][d] += z[n][d] ----------------
__global__ void k_pool(const float* __restrict__ z, const int* __restrict__ batch,
                       float* __restrict__ embs_out) {
  int idx = blockIdx.x * 256 + threadIdx.x;
  if (idx >= kN * 64) return;
  int n = idx >> 6, d = idx & 63;
  float v = z[idx];
  if (v != 0.f) atomicAdd(&embs_out[batch[n] * 64 + d], v);
}

// ---------------- per-layer state init ----------------
__global__ void k_init_layer(int* __restrict__ cluster, int* __restrict__ partner,
                             float* __restrict__ mult, int* __restrict__ nmask,
                             int set_ones) {
  int n = blockIdx.x * 256 + threadIdx.x;
  if (n >= kN) return;
  cluster[n] = n;
  partner[n] = -1;
  mult[n] = 1.0f;
  if (set_ones) nmask[n] = 1;
}

// ---------------- raw edge score + segment max (wave per edge) ----------------
__global__ __launch_bounds__(256) void k_raw(const float* __restrict__ z,
                                             const int* __restrict__ esrc,
                                             const int* __restrict__ edst,
                                             const float* __restrict__ We,
                                             const float* __restrict__ be, int layer,
                                             const int* __restrict__ emask,
                                             float* __restrict__ raws,
                                             unsigned int* __restrict__ m_enc) {
  int wv = threadIdx.x >> 6, lane = threadIdx.x & 63;
  int e = blockIdx.x * 4 + wv;
  if (e >= kE) return;
  if (emask && !emask[e]) return;
  int s = esrc[e], t = edst[e];
  float f = z[(size_t)s * 64 + lane] * We[layer * 128 + lane] +
            z[(size_t)t * 64 + lane] * We[layer * 128 + 64 + lane];
#pragma unroll
  for (int m = 32; m > 0; m >>= 1) f += __shfl_xor(f, m, 64);
  if (lane == 0) {
    float raw = f + be[layer];
    raws[e] = raw;
    unsigned int u = __float_as_uint(raw);
    u = (u & 0x80000000u) ? ~u : (u | 0x80000000u);  // order-preserving encode
    atomicMax(&m_enc[t], u);
  }
}

// ---------------- exp + denominator ----------------
__global__ void k_exp(const float* __restrict__ raws, const unsigned int* __restrict__ m_enc,
                      const int* __restrict__ edst, const int* __restrict__ emask,
                      float* __restrict__ exs, double* __restrict__ den) {
  int e = blockIdx.x * 256 + threadIdx.x;
  if (e >= kE) return;
  if (emask && !emask[e]) {
    exs[e] = 0.f;
    return;
  }
  int t = edst[e];
  unsigned int u = m_enc[t];
  u = (u & 0x80000000u) ? (u ^ 0x80000000u) : ~u;  // decode
  float m = __uint_as_float(u);
  float ex = expf(raws[e] - m);
  exs[e] = ex;
  atomicAdd(&den[t], (double)ex);
}

// ---------------- score = ex/den + 0.5, build worklist (wave-aggregated) -----
__global__ void k_scoref(const float* __restrict__ exs, const double* __restrict__ den,
                         const int* __restrict__ esrc, const int* __restrict__ edst,
                         const int* __restrict__ emask, const int* __restrict__ nmask,
                         float* __restrict__ eplus, int* __restrict__ wl,
                         int* __restrict__ cnt) {
  int e = blockIdx.x * 256 + threadIdx.x;
  int lane = threadIdx.x & 63;
  bool app = false;
  if (e < kE) {
    if (!emask || emask[e]) {
      int t = edst[e];
      float dn = (float)den[t];
      float ep = exs[e] / fmaxf(dn, 1e-16f) + 0.5f;
      eplus[e] = ep;
      int s = esrc[e];
      app = nmask[s] && nmask[t];
    } else {
      eplus[e] = 0.f;
    }
  }
  unsigned long long mb = __ballot(app);
  if (mb) {
    int leader = __ffsll((unsigned long long)mb) - 1;
    int base = 0;
    if (lane == leader) base = atomicAdd(cnt, __popcll(mb));
    base = __shfl(base, leader, 64);
    if (app) wl[base + __popcll(mb & ((1ULL << lane) - 1))] = e;
  }
}

// ---------------- greedy contraction: multi-WG locally-dominant matching -----
// ctrl[0] = grid barrier counter, ctrl[1]/ctrl[2] = ping-pong worklist counts.
// Round r reads count ctrl[1+((r+1)&1)], appends to ctrl[1+(r&1)].
__global__ __launch_bounds__(kMT) void k_match_mw(
    const int* __restrict__ esrc, const int* __restrict__ edst,
    const float* __restrict__ eplus, unsigned long long* __restrict__ best,
    int* __restrict__ wlA, int* __restrict__ wlB, unsigned int* __restrict__ avail,
    int* __restrict__ ctrl, int* __restrict__ cluster, int* __restrict__ partner,
    float* __restrict__ mult, int* __restrict__ nmask) {
  __shared__ int sh_n;
  const int tid = threadIdx.x;
  const int gtid = blockIdx.x * kMT + tid;
  const int lane = tid & 63;
  int gen = 0;

  // init avail bitmask from node mask (best[] zeroed by host-side memset)
  for (int w = gtid; w < kNW; w += kGSZ) {
    unsigned int bits = 0u;
    int base = w << 5;
    for (int j = 0; j < 32; ++j) {
      int nn = base + j;
      if (nn < kN && nmask[nn]) bits |= (1u << j);
    }
    __hip_atomic_store(&avail[w], bits, __ATOMIC_RELAXED, __HIP_MEMORY_SCOPE_AGENT);
  }
  grid_bar(&ctrl[0], &gen);

  int* cur = wlA;
  int* nxt = wlB;
  for (int r = 1; r <= 16000; ++r) {
    if (tid == 0) sh_n = ald(&ctrl[1 + ((r + 1) & 1)]);
    __syncthreads();
    const int n = sh_n;
    if (n == 0) break;
    const bool small = (n < kSMALL);
    if (small && blockIdx.x != 0) break;  // tail: block 0 finishes alone
    const int i0 = small ? tid : gtid;
    const int stp = small ? kMT : kGSZ;
    if (blockIdx.x == 0 && tid == 0) ast(&ctrl[1 + (r & 1)], 0);
    if (small) __syncthreads();

    // phase A: post round-stamped keys at both endpoints of live edges
    for (int i = i0; i < n; i += stp) {
      int e = ald(&cur[i]);
      int s = esrc[e], t = edst[e];
      unsigned int as = aldu(&avail[s >> 5]);
      unsigned int at = aldu(&avail[t >> 5]);
      if (((as >> (s & 31)) & 1u) && ((at >> (t & 31)) & 1u)) {
        unsigned long long key = mk_key(r, eplus[e], e);
        __hip_atomic_fetch_max(&best[s], key, __ATOMIC_RELAXED, __HIP_MEMORY_SCOPE_AGENT);
        if (t != s)
          __hip_atomic_fetch_max(&best[t], key, __ATOMIC_RELAXED, __HIP_MEMORY_SCOPE_AGENT);
      }
    }
    if (small) __syncthreads(); else grid_bar(&ctrl[0], &gen);

    // phase B: dominant edges match; live non-dominant edges -> next worklist
    for (int i = i0; i < n; i += stp) {
      int e = ald(&cur[i]);
      int s = esrc[e], t = edst[e];
      unsigned int as = aldu(&avail[s >> 5]);
      unsigned int at = aldu(&avail[t >> 5]);
      bool live = ((as >> (s & 31)) & 1u) && ((at >> (t & 31)) & 1u);
      bool matched = false;
      if (live) {
        unsigned long long key = mk_key(r, eplus[e], e);
        matched = (aldull(&best[s]) == key) && (t == s || aldull(&best[t]) == key);
        if (matched) {
          __hip_atomic_fetch_and(&avail[s >> 5], ~(1u << (s & 31)), __ATOMIC_RELAXED,
                                 __HIP_MEMORY_SCOPE_AGENT);
          __hip_atomic_fetch_and(&avail[t >> 5], ~(1u << (t & 31)), __ATOMIC_RELAXED,
                                 __HIP_MEMORY_SCOPE_AGENT);
          cluster[t] = s;
          partner[s] = t;
          mult[s] = eplus[e];
          if (t != s) nmask[t] = 0;
        }
      }
      bool survive = live && !matched;
      unsigned long long mb = __ballot(survive);
      if (mb) {
        int leader = __ffsll((unsigned long long)mb) - 1;
        int base = 0;
        if (lane == leader)
          base = __hip_atomic_fetch_add(&ctrl[1 + (r & 1)], (int)__popcll(mb),
                                        __ATOMIC_RELAXED, __HIP_MEMORY_SCOPE_AGENT);
        base = __shfl(base, leader, 64);
        if (survive) ast(&nxt[base + __popcll(mb & ((1ULL << lane) - 1))], e);
      }
    }
    if (small) __syncthreads(); else grid_bar(&ctrl[0], &gen);
    int* tmp = cur; cur = nxt; nxt = tmp;
  }
}

// ---------------- merged features: <=2 members per cluster, no atomics -------
__global__ void k_newx(const float* __restrict__ z, const int* __restrict__ cluster,
                       const int* __restrict__ partner, const float* __restrict__ mult,
                       float* __restrict__ zo) {
  int idx = blockIdx.x * 256 + threadIdx.x;
  if (idx >= kN * 64) return;
  int n = idx >> 6, d = idx & 63;
  float v = 0.f;
  if (cluster[n] == n) {
    v = z[idx];
    int p = partner[n];
    if (p >= 0 && p != n) v += z[(size_t)p * 64 + d];
    v *= mult[n];
  }
  zo[idx] = v;
}

// ---------------- edge remap + hash-dedup (keep min edge id per key) ---------
__global__ void k_remap(const int* __restrict__ esrc, const int* __restrict__ edst,
                        const int* __restrict__ cluster, const int* __restrict__ emask,
                        int* __restrict__ esrcn, int* __restrict__ edstn,
                        int* __restrict__ hkey, int* __restrict__ hmin,
                        int* __restrict__ hslot) {
  int e = blockIdx.x * 256 + threadIdx.x;
  if (e >= kE) return;
  int ns = cluster[esrc[e]];
  int nt = cluster[edst[e]];
  esrcn[e] = ns;
  edstn[e] = nt;
  if (emask && !emask[e]) return;
  int key = ns * kN + nt;  // < 9e8, fits int32
  unsigned int h = (((unsigned int)key * 2654435761u) >> 13) & (kHSZ - 1);
  while (true) {
    int old = atomicCAS(&hkey[h], -1, key);
    if (old == -1 || old == key) break;
    h = (h + 1) & (kHSZ - 1);
  }
  atomicMin(&hmin[h], e);
  hslot[e] = (int)h;
}

__global__ void k_dedup(const int* __restrict__ emask, const int* __restrict__ hmin,
                        const int* __restrict__ hslot, int* __restrict__ emaskn) {
  int e = blockIdx.x * 256 + threadIdx.x;
  if (e >= kE) return;
  int keep = 0;
  if (!emask || emask[e]) keep = (hmin[hslot[e]] == e) ? 1 : 0;
  emaskn[e] = keep;
}

// ---------------- final FC: out = concat(embs) @ W_fc + b_fc ----------------
__global__ void k_final(const float* __restrict__ embs, const float* __restrict__ Wfc,
                        const float* __restrict__ bfc, float* __restrict__ out) {
  int tid = threadIdx.x;
  if (tid >= kG * 10) return;
  int g = tid / 10, c = tid % 10;
  float acc = bfc[c];
  for (int l = 0; l < 3; ++l)
    for (int d = 0; d < 64; ++d)
      acc += embs[l * (kG * 64) + g * 64 + d] * Wfc[(l * 64 + d) * 10 + c];
  out[g * 10 + c] = acc;
}

extern "C" void kernel_launch(void* const* d_in, const int* in_sizes, int n_in,
                              void* d_out, int out_size, void* d_ws, size_t ws_size,
                              hipStream_t stream) {
  (void)in_sizes; (void)n_in; (void)out_size; (void)ws_size;
  const float* x = (const float*)d_in[0];
  const int* ei = (const int*)d_in[1];  // [2,E]: src = ei, dst = ei + kE
  const int* batch = (const int*)d_in[2];
  const float* Wemb = (const float*)d_in[3];
  const float* We = (const float*)d_in[4];
  const float* be = (const float*)d_in[5];
  const float* Wfc = (const float*)d_in[6];
  const float* bfc = (const float*)d_in[7];
  float* out = (float*)d_out;

  char* ws = (char*)d_ws;
  size_t off = 0;
  auto alloc = [&](size_t bytes) -> void* {
    void* p = ws + off;
    off = (off + bytes + 255) & ~(size_t)255;
    return p;
  };
  float* z0 = (float*)alloc((size_t)kN * 64 * 4);
  float* z1 = (float*)alloc((size_t)kN * 64 * 4);
  float* raws = (float*)alloc((size_t)kE * 4);
  float* exs = (float*)alloc((size_t)kE * 4);
  float* eplus = (float*)alloc((size_t)kE * 4);
  unsigned int* m_enc = (unsigned int*)alloc((size_t)kN * 4);
  double* den = (double*)alloc((size_t)kN * 8);
  unsigned long long* best = (unsigned long long*)alloc((size_t)kN * 8);
  int* cluster = (int*)alloc((size_t)kN * 4);
  int* partner = (int*)alloc((size_t)kN * 4);
  float* mult = (float*)alloc((size_t)kN * 4);
  int* nmask = (int*)alloc((size_t)kN * 4);
  unsigned int* avail = (unsigned int*)alloc((size_t)kNW * 4);
  int* esrc1 = (int*)alloc((size_t)kE * 4);
  int* edst1 = (int*)alloc((size_t)kE * 4);
  int* emask1 = (int*)alloc((size_t)kE * 4);
  int* wlA = (int*)alloc((size_t)kE * 4);
  int* wlB = (int*)alloc((size_t)kE * 4);
  int* hkey = (int*)alloc((size_t)kHSZ * 4);
  int* hmin = (int*)alloc((size_t)kHSZ * 4);
  float* embs = (float*)alloc((size_t)3 * kG * 64 * 4);
  int* ctrl = (int*)alloc(256);

  const int gN = (kN + 255) / 256;          // 118
  const int gND = (kN * 64) / 256;          // 7500
  const int gE = (kE + 255) / 256;          // 938
  const int gEW = kE / 4;                   // 60000 (wave per edge)

  hipMemsetAsync(embs, 0, (size_t)3 * kG * 64 * 4, stream);

  k_embed<<<kN / 16, 256, 0, stream>>>(x, Wemb, z0);
  k_pool<<<gND, 256, 0, stream>>>(z0, batch, embs);  // embs[0]

  // ---------------- layer 1 ----------------
  k_init_layer<<<gN, 256, 0, stream>>>(cluster, partner, mult, nmask, 1);
  hipMemsetAsync(m_enc, 0, (size_t)kN * 4, stream);
  hipMemsetAsync(den, 0, (size_t)kN * 8, stream);
  hipMemsetAsync(best, 0, (size_t)kN * 8, stream);
  hipMemsetAsync(ctrl, 0, 256, stream);
  hipMemsetAsync(hkey, 0xFF, (size_t)kHSZ * 4, stream);
  hipMemsetAsync(hmin, 0x7F, (size_t)kHSZ * 4, stream);
  k_raw<<<gEW, 256, 0, stream>>>(z0, ei, ei + kE, We, be, 0, nullptr, raws, m_enc);
  k_exp<<<gE, 256, 0, stream>>>(raws, m_enc, ei + kE, nullptr, exs, den);
  k_scoref<<<gE, 256, 0, stream>>>(exs, den, ei, ei + kE, nullptr, nmask, eplus, wlA,
                                   &ctrl[1]);
  k_match_mw<<<kMB, kMT, 0, stream>>>(ei, ei + kE, eplus, best, wlA, wlB, avail, ctrl,
                                      cluster, partner, mult, nmask);
  k_newx<<<gND, 256, 0, stream>>>(z0, cluster, partner, mult, z1);
  k_pool<<<gND, 256, 0, stream>>>(z1, batch, embs + kG * 64);  // embs[1]
  k_remap<<<gE, 256, 0, stream>>>(ei, ei + kE, cluster, nullptr, esrc1, edst1, hkey,
                                  hmin, wlA);
  k_dedup<<<gE, 256, 0, stream>>>(nullptr, hmin, wlA, emask1);

  // ---------------- layer 2 ----------------
  k_init_layer<<<gN, 256, 0, stream>>>(cluster, partner, mult, nmask, 0);
  hipMemsetAsync(m_enc, 0, (size_t)kN * 4, stream);
  hipMemsetAsync(den, 0, (size_t)kN * 8, stream);
  hipMemsetAsync(best, 0, (size_t)kN * 8, stream);
  hipMemsetAsync(ctrl, 0, 256, stream);
  k_raw<<<gEW, 256, 0, stream>>>(z1, esrc1, edst1, We, be, 1, emask1, raws, m_enc);
  k_exp<<<gE, 256, 0, stream>>>(raws, m_enc, edst1, emask1, exs, den);
  k_scoref<<<gE, 256, 0, stream>>>(exs, den, esrc1, edst1, emask1, nmask, eplus, wlA,
                                   &ctrl[1]);
  k_match_mw<<<kMB, kMT, 0, stream>>>(esrc1, edst1, eplus, best, wlA, wlB, avail, ctrl,
                                      cluster, partner, mult, nmask);
  k_newx<<<gND, 256, 0, stream>>>(z1, cluster, partner, mult, z0);
  k_pool<<<gND, 256, 0, stream>>>(z0, batch, embs + 2 * kG * 64);  // embs[2]

  k_final<<<1, 640, 0, stream>>>(embs, Wfc, bfc, out);
}

// Round 3
// 1354.621 us; speedup vs baseline: 8.4324x; 1.0000x over previous
//
#include <hip/hip_runtime.h>
#include <math.h>

#define kN 30000
#define kE 240000
#define kG 64
#define kHSZ (1 << 19)
#define kNW 938  // ceil(30000/32)
#define kMB 64
#define kMT 1024
#define kGSZ (kMB * kMT)
#define kCAP 4      // ceil(kE / kGSZ)
#define kSMALL 8192

typedef unsigned long long ull;

// ---------------- atomic helpers (AGENT scope, coherent point) ----------------
__device__ __forceinline__ int ald(const int* p) {
  return __hip_atomic_load(p, __ATOMIC_RELAXED, __HIP_MEMORY_SCOPE_AGENT);
}
__device__ __forceinline__ unsigned aldu(const unsigned* p) {
  return __hip_atomic_load(p, __ATOMIC_RELAXED, __HIP_MEMORY_SCOPE_AGENT);
}
__device__ __forceinline__ ull aldull(const ull* p) {
  return __hip_atomic_load(p, __ATOMIC_RELAXED, __HIP_MEMORY_SCOPE_AGENT);
}
__device__ __forceinline__ void amax64(ull* p, ull v) {
  __hip_atomic_fetch_max(p, v, __ATOMIC_RELAXED, __HIP_MEMORY_SCOPE_AGENT);
}
__device__ __forceinline__ unsigned enc_f(float x) {
  unsigned u = __float_as_uint(x);
  return (u & 0x80000000u) ? ~u : (u | 0x80000000u);
}
__device__ __forceinline__ float dec_f(unsigned u) {
  u = (u & 0x80000000u) ? (u ^ 0x80000000u) : ~u;
  return __uint_as_float(u);
}
// key: (stamp << 50) | enc(score) << 18 | (262143 - e); atomicMax semantics =
// (newest stamp, highest score, lowest edge id) wins.
__device__ __forceinline__ ull mk_key(int r, unsigned enc, int e) {
  return ((ull)r << 50) | ((ull)enc << 18) | (ull)(262143 - e);
}

// centralized grid barrier: 64 co-resident WGs (low VGPR/LDS => always fits)
__device__ __forceinline__ void round_bar(int* bar, int* gen) {
  __syncthreads();
  if (threadIdx.x == 0) {
    int g = ++(*gen);
    __hip_atomic_fetch_add(bar, 1, __ATOMIC_ACQ_REL, __HIP_MEMORY_SCOPE_AGENT);
    while (__hip_atomic_load(bar, __ATOMIC_ACQUIRE, __HIP_MEMORY_SCOPE_AGENT) < kMB * g)
      __builtin_amdgcn_s_sleep(2);
  }
  __syncthreads();
}

// ---------------- embed: z = x @ W_embed ----------------
__global__ __launch_bounds__(256) void k_embed(const float* __restrict__ x,
                                               const float* __restrict__ W,
                                               float* __restrict__ z) {
  __shared__ float sW[128 * 64];  // 32 KB
  int tid = threadIdx.x;
  for (int i = tid; i < 128 * 64; i += 256) sW[i] = W[i];
  __syncthreads();
  int lane = tid & 63, sub = tid >> 6;
  int row0 = blockIdx.x * 16;
  for (int r = sub; r < 16; r += 4) {
    int n = row0 + r;
    if (n >= kN) continue;
    const float* xr = x + (size_t)n * 128;
    float acc = 0.f;
#pragma unroll
    for (int k = 0; k < 128; ++k) acc = fmaf(xr[k], sW[k * 64 + lane], acc);
    z[(size_t)n * 64 + lane] = acc;
  }
}

// ---------------- per-layer init: state + counters (replaces memsets) --------
__global__ void k_init(int* __restrict__ cluster, int* __restrict__ partner,
                       float* __restrict__ mult, int* __restrict__ nmask,
                       unsigned* __restrict__ m_enc, double* __restrict__ den,
                       ull* __restrict__ best, int* __restrict__ cnt,
                       int* __restrict__ ctrl, int* __restrict__ hkey,
                       int* __restrict__ hmin, float* __restrict__ embs,
                       int layer1) {
  int S = gridDim.x * blockDim.x;
  for (int i = blockIdx.x * blockDim.x + threadIdx.x; i < kHSZ; i += S) {
    if (i < kN) {
      cluster[i] = i;
      partner[i] = -1;
      mult[i] = 1.f;
      if (layer1) nmask[i] = 1;
      m_enc[i] = 0u;
      den[i] = 0.0;
    }
    if (i < 2 * kN) best[i] = 0ULL;  // both parities
    if (i < 16384) cnt[i] = 0;
    if (i < 8) ctrl[i] = 0;
    if (layer1) {
      hkey[i] = -1;
      hmin[i] = 0x7fffffff;
      if (i < 3 * kG * 64) embs[i] = 0.f;
    }
  }
}

// ---------------- raw edge score + segment max (wave per edge) ----------------
__global__ __launch_bounds__(256) void k_raw(const float* __restrict__ z,
                                             const int* __restrict__ esrc,
                                             const int* __restrict__ edst,
                                             const float* __restrict__ We,
                                             const float* __restrict__ be, int layer,
                                             const int* __restrict__ emask,
                                             float* __restrict__ raws,
                                             unsigned* __restrict__ m_enc) {
  int wv = threadIdx.x >> 6, lane = threadIdx.x & 63;
  int e = blockIdx.x * 4 + wv;
  if (e >= kE) return;
  if (emask && !emask[e]) return;
  int s = esrc[e], t = edst[e];
  float f = z[(size_t)s * 64 + lane] * We[layer * 128 + lane] +
            z[(size_t)t * 64 + lane] * We[layer * 128 + 64 + lane];
#pragma unroll
  for (int m = 32; m > 0; m >>= 1) f += __shfl_xor(f, m, 64);
  if (lane == 0) {
    float raw = f + be[layer];
    raws[e] = raw;
    atomicMax(&m_enc[t], enc_f(raw));
  }
}

// ---------------- matching: softmax-finish + locally-dominant contraction ----
// best is parity-split: stamp x lives in best[(x&1)*kN + node]. Single barrier
// per round: check stamp-r winners (parity r&1) and post stamp-(r+1) keys
// (parity (r+1)&1) in one pass -- no check-vs-post interference.
__global__ __launch_bounds__(kMT) void k_match_mw(
    const int* __restrict__ esrc, const int* __restrict__ edst,
    const float* __restrict__ raws, const unsigned* __restrict__ m_enc,
    const int* __restrict__ emask, double* __restrict__ den,
    ull* __restrict__ best, unsigned* __restrict__ avail,
    int4* __restrict__ wl, int4* __restrict__ wlB, int* __restrict__ ctrl,
    int* __restrict__ cnt, int* __restrict__ cluster, int* __restrict__ partner,
    float* __restrict__ mult, int* __restrict__ nmask) {
  const int tid = threadIdx.x;
  const int gtid = blockIdx.x * kMT + tid;
  const int lane = tid & 63;
  int gen = 0;

  // ---- pre-phase: avail init + softmax denominator ----
  for (int w = gtid; w < kNW; w += kGSZ) {
    unsigned bits = 0u;
    int base = w << 5;
    for (int j = 0; j < 32; ++j) {
      int nn = base + j;
      if (nn < kN && nmask[nn]) bits |= (1u << j);
    }
    __hip_atomic_store(&avail[w], bits, __ATOMIC_RELAXED, __HIP_MEMORY_SCOPE_AGENT);
  }
  for (int e = gtid; e < kE; e += kGSZ) {
    if (emask && !emask[e]) continue;
    int t = edst[e];
    float ex = expf(raws[e] - dec_f(m_enc[t]));
    atomicAdd(&den[t], (double)ex);
  }
  round_bar(&ctrl[0], &gen);

  // ---- build register-resident worklist + post stamp-1 keys (parity 1) ----
  int es[kCAP], et[kCAP], ee[kCAP];
  unsigned en[kCAP];
  int myc = 0;
#pragma unroll
  for (int k = 0; k < kCAP; ++k) {
    ee[k] = -1;
    int e = gtid + k * kGSZ;
    if (e >= kE) continue;
    if (emask && !emask[e]) continue;
    int s = esrc[e], t = edst[e];
    if (!((aldu(&avail[s >> 5]) >> (s & 31)) & 1u)) continue;
    if (!((aldu(&avail[t >> 5]) >> (t & 31)) & 1u)) continue;
    float ex = expf(raws[e] - dec_f(m_enc[t]));
    float ep = ex / fmaxf((float)den[t], 1e-16f) + 0.5f;
    unsigned u = enc_f(ep);
    es[k] = s; et[k] = t; en[k] = u; ee[k] = e;
    ++myc;
    ull key = mk_key(1, u, e);
    amax64(&best[kN + s], key);
    if (t != s) amax64(&best[kN + t], key);
  }
  {
    int a = myc;
#pragma unroll
    for (int m = 32; m; m >>= 1) a += __shfl_xor(a, m, 64);
    if (lane == 0 && a)
      __hip_atomic_fetch_add(&cnt[0], a, __ATOMIC_RELAXED, __HIP_MEMORY_SCOPE_AGENT);
  }

  // ---- single-barrier rounds ----
  int r = 1;
  bool to_tail = false;
  for (; r < 16000; ++r) {
    round_bar(&ctrl[0], &gen);
    int tot = ald(&cnt[r - 1]);
    if (tot == 0) return;
    if (tot < kSMALL) { to_tail = true; break; }
    ull* bchk = best + (size_t)(r & 1) * kN;
    ull* bpost = best + (size_t)((r + 1) & 1) * kN;
    int alive = 0;
#pragma unroll
    for (int k = 0; k < kCAP; ++k) {
      if (ee[k] < 0) continue;
      int s = es[k], t = et[k];
      if (!((aldu(&avail[s >> 5]) >> (s & 31)) & 1u) ||
          !((aldu(&avail[t >> 5]) >> (t & 31)) & 1u)) {
        ee[k] = -1;
        continue;
      }
      ull key = mk_key(r, en[k], ee[k]);
      bool m1 = (aldull(&bchk[s]) == key) && (t == s || aldull(&bchk[t]) == key);
      if (m1) {
        __hip_atomic_fetch_and(&avail[s >> 5], ~(1u << (s & 31)), __ATOMIC_RELAXED,
                               __HIP_MEMORY_SCOPE_AGENT);
        __hip_atomic_fetch_and(&avail[t >> 5], ~(1u << (t & 31)), __ATOMIC_RELAXED,
                               __HIP_MEMORY_SCOPE_AGENT);
        cluster[t] = s;
        partner[s] = t;
        mult[s] = dec_f(en[k]);
        if (t != s) nmask[t] = 0;
        ee[k] = -1;
      } else {
        ull k2 = mk_key(r + 1, en[k], ee[k]);
        amax64(&bpost[s], k2);
        if (t != s) amax64(&bpost[t], k2);
        ++alive;
      }
    }
    int a = alive;
#pragma unroll
    for (int m = 32; m; m >>= 1) a += __shfl_xor(a, m, 64);
    if (lane == 0 && a)
      __hip_atomic_fetch_add(&cnt[r], a, __ATOMIC_RELAXED, __HIP_MEMORY_SCOPE_AGENT);
  }
  if (!to_tail) return;

  // ---- handoff: compact surviving entries to global wl ----
#pragma unroll
  for (int k = 0; k < kCAP; ++k) {
    bool act = (ee[k] >= 0);
    unsigned long long mb = __ballot(act);
    if (!mb) continue;
    int leader = __ffsll(mb) - 1;
    int base = 0;
    if (lane == leader)
      base = __hip_atomic_fetch_add(&ctrl[1], (int)__popcll(mb), __ATOMIC_RELAXED,
                                    __HIP_MEMORY_SCOPE_AGENT);
    base = __shfl(base, leader, 64);
    if (act)
      wl[base + __popcll(mb & ((1ULL << lane) - 1))] =
          make_int4(es[k], et[k], (int)en[k], ee[k]);
  }
  round_bar(&ctrl[0], &gen);
  if (blockIdx.x != 0) return;

  // ---- tail: block 0 alone, avail mirrored in LDS ----
  __shared__ unsigned lav[kNW];
  __shared__ int ls;
  for (int w = tid; w < kNW; w += kMT) lav[w] = aldu(&avail[w]);
  __syncthreads();
  int n = ald(&ctrl[1]);
  int4* cur = wl;
  int4* nxt = wlB;
  for (int rr = r; n > 0 && rr < 16300; ++rr) {
    if (tid == 0) ls = 0;
    __syncthreads();
    ull* bchk = best + (size_t)(rr & 1) * kN;
    ull* bpost = best + (size_t)((rr + 1) & 1) * kN;
    for (int i = tid; i < n; i += kMT) {
      int4 E = cur[i];
      int s = E.x, t = E.y, e = E.w;
      unsigned u = (unsigned)E.z;
      if (!((lav[s >> 5] >> (s & 31)) & 1u) || !((lav[t >> 5] >> (t & 31)) & 1u))
        continue;
      ull key = mk_key(rr, u, e);
      bool m1 = (aldull(&bchk[s]) == key) && (t == s || aldull(&bchk[t]) == key);
      if (m1) {
        atomicAnd(&lav[s >> 5], ~(1u << (s & 31)));
        atomicAnd(&lav[t >> 5], ~(1u << (t & 31)));
        cluster[t] = s;
        partner[s] = t;
        mult[s] = dec_f(u);
        if (t != s) nmask[t] = 0;
      } else {
        ull k2 = mk_key(rr + 1, u, e);
        amax64(&bpost[s], k2);
        if (t != s) amax64(&bpost[t], k2);
        int p = atomicAdd(&ls, 1);
        nxt[p] = E;
      }
    }
    __syncthreads();
    n = ls;
    int4* tmp = cur;
    cur = nxt;
    nxt = tmp;
  }
}

// ---------------- fused merged-features + graph pooling ----------------------
// batch[] is sorted -> run-length accumulate, one atomic per (graph,dim) run.
__global__ __launch_bounds__(256) void k_newx_pool(
    const float* __restrict__ z, const int* __restrict__ cluster,
    const int* __restrict__ partner, const float* __restrict__ mult,
    const int* __restrict__ batch, float* __restrict__ zo,
    float* __restrict__ embs_g) {
  int tid = threadIdx.x;
  int d = tid & 63;
  int n0 = blockIdx.x * 128 + (tid >> 6) * 32;
  float acc = 0.f;
  int curg = -1;
  for (int k = 0; k < 32; ++k) {
    int n = n0 + k;
    if (n >= kN) break;
    int g = batch[n];  // wave-uniform load
    if (g != curg) {
      if (curg >= 0 && acc != 0.f) atomicAdd(&embs_g[curg * 64 + d], acc);
      acc = 0.f;
      curg = g;
    }
    float v;
    if (cluster) {
      v = 0.f;
      if (cluster[n] == n) {
        v = z[(size_t)n * 64 + d];
        int p = partner[n];
        if (p >= 0 && p != n) v += z[(size_t)p * 64 + d];
        v *= mult[n];
      }
    } else {
      v = z[(size_t)n * 64 + d];
    }
    if (zo) zo[(size_t)n * 64 + d] = v;
    acc += v;
  }
  if (curg >= 0 && acc != 0.f) atomicAdd(&embs_g[curg * 64 + d], acc);
}

// ---------------- edge remap + hash-dedup (keep min edge id per key) ---------
__global__ void k_remap(const int* __restrict__ esrc, const int* __restrict__ edst,
                        const int* __restrict__ cluster, const int* __restrict__ emask,
                        int* __restrict__ esrcn, int* __restrict__ edstn,
                        int* __restrict__ hkey, int* __restrict__ hmin,
                        int* __restrict__ hslot) {
  int e = blockIdx.x * 256 + threadIdx.x;
  if (e >= kE) return;
  int ns = cluster[esrc[e]];
  int nt = cluster[edst[e]];
  esrcn[e] = ns;
  edstn[e] = nt;
  if (emask && !emask[e]) return;
  int key = ns * kN + nt;  // < 9e8, fits int32
  unsigned h = (((unsigned)key * 2654435761u) >> 13) & (kHSZ - 1);
  while (true) {
    int old = atomicCAS(&hkey[h], -1, key);
    if (old == -1 || old == key) break;
    h = (h + 1) & (kHSZ - 1);
  }
  atomicMin(&hmin[h], e);
  hslot[e] = (int)h;
}

__global__ void k_dedup(const int* __restrict__ emask, const int* __restrict__ hmin,
                        const int* __restrict__ hslot, int* __restrict__ emaskn) {
  int e = blockIdx.x * 256 + threadIdx.x;
  if (e >= kE) return;
  int keep = 0;
  if (!emask || emask[e]) keep = (hmin[hslot[e]] == e) ? 1 : 0;
  emaskn[e] = keep;
}

// ---------------- final FC: out = concat(embs) @ W_fc + b_fc ----------------
__global__ void k_final(const float* __restrict__ embs, const float* __restrict__ Wfc,
                        const float* __restrict__ bfc, float* __restrict__ out) {
  int tid = threadIdx.x;
  if (tid >= kG * 10) return;
  int g = tid / 10, c = tid % 10;
  float acc = bfc[c];
  for (int l = 0; l < 3; ++l)
    for (int d = 0; d < 64; ++d)
      acc += embs[l * (kG * 64) + g * 64 + d] * Wfc[(l * 64 + d) * 10 + c];
  out[g * 10 + c] = acc;
}

extern "C" void kernel_launch(void* const* d_in, const int* in_sizes, int n_in,
                              void* d_out, int out_size, void* d_ws, size_t ws_size,
                              hipStream_t stream) {
  (void)in_sizes; (void)n_in; (void)out_size; (void)ws_size;
  const float* x = (const float*)d_in[0];
  const int* ei = (const int*)d_in[1];  // [2,E]: src = ei, dst = ei + kE
  const int* batch = (const int*)d_in[2];
  const float* Wemb = (const float*)d_in[3];
  const float* We = (const float*)d_in[4];
  const float* be = (const float*)d_in[5];
  const float* Wfc = (const float*)d_in[6];
  const float* bfc = (const float*)d_in[7];
  float* out = (float*)d_out;

  char* ws = (char*)d_ws;
  size_t off = 0;
  auto alloc = [&](size_t bytes) -> void* {
    void* p = ws + off;
    off = (off + bytes + 255) & ~(size_t)255;
    return p;
  };
  float* z0 = (float*)alloc((size_t)kN * 64 * 4);
  float* z1 = (float*)alloc((size_t)kN * 64 * 4);
  float* raws = (float*)alloc((size_t)kE * 4);
  unsigned* m_enc = (unsigned*)alloc((size_t)kN * 4);
  double* den = (double*)alloc((size_t)kN * 8);
  ull* best = (ull*)alloc((size_t)2 * kN * 8);  // parity-split
  int* cluster = (int*)alloc((size_t)kN * 4);
  int* partner = (int*)alloc((size_t)kN * 4);
  float* mult = (float*)alloc((size_t)kN * 4);
  int* nmask = (int*)alloc((size_t)kN * 4);
  unsigned* avail = (unsigned*)alloc((size_t)kNW * 4);
  int* esrc1 = (int*)alloc((size_t)kE * 4);
  int* edst1 = (int*)alloc((size_t)kE * 4);
  int* emask1 = (int*)alloc((size_t)kE * 4);
  int4* wl = (int4*)alloc((size_t)kE * 16);
  int4* wlB = (int4*)alloc((size_t)kE * 16);
  int* hkey = (int*)alloc((size_t)kHSZ * 4);
  int* hmin = (int*)alloc((size_t)kHSZ * 4);
  float* embs = (float*)alloc((size_t)3 * kG * 64 * 4);
  int* cnt = (int*)alloc((size_t)16384 * 4);
  int* ctrl = (int*)alloc(256);
  int* hslot = (int*)wlB;  // free at remap time

  const int gE = (kE + 255) / 256;  // 938
  const int gEW = kE / 4;           // 60000 (wave per edge)
  const int gNP = (kN + 127) / 128; // 235

  // ---------------- layer 1 ----------------
  k_init<<<512, 256, 0, stream>>>(cluster, partner, mult, nmask, m_enc, den, best,
                                  cnt, ctrl, hkey, hmin, embs, 1);
  k_embed<<<kN / 16, 256, 0, stream>>>(x, Wemb, z0);
  k_newx_pool<<<gNP, 256, 0, stream>>>(z0, nullptr, nullptr, nullptr, batch, nullptr,
                                       embs);  // embs[0]
  k_raw<<<gEW, 256, 0, stream>>>(z0, ei, ei + kE, We, be, 0, nullptr, raws, m_enc);
  k_match_mw<<<kMB, kMT, 0, stream>>>(ei, ei + kE, raws, m_enc, nullptr, den, best,
                                      avail, wl, wlB, ctrl, cnt, cluster, partner,
                                      mult, nmask);
  k_newx_pool<<<gNP, 256, 0, stream>>>(z0, cluster, partner, mult, batch, z1,
                                       embs + kG * 64);  // z1 + embs[1]
  k_remap<<<gE, 256, 0, stream>>>(ei, ei + kE, cluster, nullptr, esrc1, edst1, hkey,
                                  hmin, hslot);
  k_dedup<<<gE, 256, 0, stream>>>(nullptr, hmin, hslot, emask1);

  // ---------------- layer 2 ----------------
  k_init<<<512, 256, 0, stream>>>(cluster, partner, mult, nmask, m_enc, den, best,
                                  cnt, ctrl, hkey, hmin, embs, 0);
  k_raw<<<gEW, 256, 0, stream>>>(z1, esrc1, edst1, We, be, 1, emask1, raws, m_enc);
  k_match_mw<<<kMB, kMT, 0, stream>>>(esrc1, edst1, raws, m_enc, emask1, den, best,
                                      avail, wl, wlB, ctrl, cnt, cluster, partner,
                                      mult, nmask);
  k_newx_pool<<<gNP, 256, 0, stream>>>(z1, cluster, partner, mult, batch, nullptr,
                                       embs + 2 * kG * 64);  // embs[2]

  k_final<<<1, 640, 0, stream>>>(embs, Wfc, bfc, out);
}